// Round 1
// baseline (1002.084 us; speedup 1.0000x reference)
//
#include <hip/hip_runtime.h>

// Problem constants
#define NN   65536      // N nodes
#define NE   524288     // E edges
#define NGR  64         // B graphs
#define EPG  8192       // edges per graph
#define NPGC 1024       // nodes per graph

// Output float offsets in d_out
#define O1 7913472      // ei_new (2*E)
#define O2 8962048      // ea_new (E)
#define O3 9486336      // batch_out (30912)
#define O4 9517248      // perm (30912)
#define O5 9548160      // score_perm (30912)
#define O6 9579072      // sentence_scores (4096)
#define O7 9583168      // sentence_batch (4096)
#define O8 9587264      // keep (E)

// Scratch placement inside d_out (float offsets). Lifetime-checked:
//  ybuf [0, 8388608): dies after last k_gemm (before k_mask_init)
//  deg/z in O1 region: die before k_edges writes O1
//  score at O8: dies after k_topk, before k_edges writes O8
//  mask ints at [0,65536): written after gemm, read by k_edges, clobbered by k_xout (last)
#define DEG_OFF 8388608
#define Z_OFF   8454144
#define SCORE_OFF O8

__device__ __forceinline__ unsigned monof(float f) {
  unsigned u = __float_as_uint(f);
  return (u & 0x80000000u) ? ~u : (u | 0x80000000u);  // ascending monotone map
}

__global__ void k_init(float* __restrict__ deg, float* __restrict__ z) {
  int n = blockIdx.x * 256 + threadIdx.x;
  if (n < NN) { deg[n] = 1.0f; z[n] = 0.0f; }
}

__global__ void k_deg(const int* __restrict__ ei, const float* __restrict__ w,
                      float* __restrict__ deg) {
  int e = blockIdx.x * 256 + threadIdx.x;
  if (e < NE) unsafeAtomicAdd(&deg[ei[NE + e]], w[e]);
}

__global__ void k_dinv(float* __restrict__ deg) {
  int n = blockIdx.x * 256 + threadIdx.x;
  if (n < NN) { float d = deg[n]; deg[n] = d > 0.0f ? 1.0f / sqrtf(d) : 0.0f; }
}

// Aggregate x over normalized adjacency into ybuf (chunk of 32 graphs).
// One block = (graph g, 16-column chunk cc). 16 lanes cooperate per edge,
// lane j owns column c0+j (no runtime-indexed register arrays).
__global__ __launch_bounds__(256) void k_aggx(const float* __restrict__ x,
    const int* __restrict__ ei, const float* __restrict__ w,
    const float* __restrict__ dinv, float* __restrict__ ybuf, int gbase, int nch) {
  extern __shared__ float acc[];  // [1024][16] = 64 KB
  int bid = blockIdx.x;
  int g  = bid % nch;             // same graph -> same XCD (bid mod 8 constant)
  int cc = bid / nch;
  int gg = gbase + g;
  int c0 = cc * 16;
  int t = threadIdx.x;
  int nbase = gg << 10;
  // init with self-loop term: acc = dinv[n] * x[n]  (final *dinv[c] gives dinv^2 x)
  for (int s = 0; s < 64; ++s) {
    int i = t + s * 256;
    int n = i >> 4, jj = i & 15;
    acc[i] = dinv[nbase + n] * x[(nbase + n) * 256 + c0 + jj];
  }
  __syncthreads();
  int j = t & 15, slot = t >> 4;  // 16 edge-slots x 16 columns
  int ebase = gg * EPG;
  for (int e0 = slot; e0 < EPG; e0 += 64) {   // 4 independent edges in flight
    int   rows[4], cls[4];
    float coefs[4], xv[4];
#pragma unroll
    for (int u = 0; u < 4; ++u) {
      int e = ebase + e0 + u * 16;
      rows[u]  = ei[e];
      cls[u]   = ei[NE + e] & 1023;
      coefs[u] = w[e] * dinv[rows[u]];
      xv[u]    = x[rows[u] * 256 + c0 + j];
    }
#pragma unroll
    for (int u = 0; u < 4; ++u)
      atomicAdd(&acc[cls[u] * 16 + j], coefs[u] * xv[u]);
  }
  __syncthreads();
  for (int s = 0; s < 64; ++s) {
    int i = t + s * 256;
    int n = i >> 4;
    ybuf[((g << 10) + n) * 256 + c0 + (i & 15)] = dinv[nbase + n] * acc[i];
  }
}

// fp32 GEMM y(32768x256) @ W1(256x512), fused +b1 -> LeakyReLU -> dot W2 -> atomic z
// BM=64, BN=128, BK=32, 256 threads, acc 4x8 per thread.
__global__ __launch_bounds__(256) void k_gemm(const float* __restrict__ ybuf,
    const float* __restrict__ W1, const float* __restrict__ b1,
    const float* __restrict__ W2, float* __restrict__ z, int node_base) {
  __shared__ float As[32][68];    // [k][row], padded
  __shared__ float Bs[32][132];   // [k][col], padded
  int bx = blockIdx.x & 3;        // 4 col-blocks of 128
  int by = blockIdx.x >> 2;       // 512 row-blocks of 64
  int t = threadIdx.x;
  int tx = t & 15, ty = t >> 4;
  int row0 = by * 64;
  float acc[4][8] = {};
  for (int kt = 0; kt < 256; kt += 32) {
    __syncthreads();
#pragma unroll
    for (int s = 0; s < 8; ++s) {         // A: 64x32
      int i = t + s * 256;
      As[i & 31][i >> 5] = ybuf[(row0 + (i >> 5)) * 256 + kt + (i & 31)];
    }
#pragma unroll
    for (int s = 0; s < 16; ++s) {        // B: 32x128
      int i = t + s * 256;
      Bs[i >> 7][i & 127] = W1[(kt + (i >> 7)) * 512 + bx * 128 + (i & 127)];
    }
    __syncthreads();
#pragma unroll
    for (int kk = 0; kk < 32; ++kk) {
      float4 a4  = *(const float4*)&As[kk][ty * 4];
      float4 b4a = *(const float4*)&Bs[kk][tx * 8];
      float4 b4b = *(const float4*)&Bs[kk][tx * 8 + 4];
      float a[4]  = {a4.x, a4.y, a4.z, a4.w};
      float bb[8] = {b4a.x, b4a.y, b4a.z, b4a.w, b4b.x, b4b.y, b4b.z, b4b.w};
#pragma unroll
      for (int r = 0; r < 4; ++r)
#pragma unroll
        for (int c = 0; c < 8; ++c)
          acc[r][c] += a[r] * bb[c];
    }
  }
  // epilogue: +b1, LeakyReLU, dot W2, reduce over tx, atomic into z
  int c0 = bx * 128 + tx * 8;
  float b1v[8], w2v[8];
#pragma unroll
  for (int c = 0; c < 8; ++c) { b1v[c] = b1[c0 + c]; w2v[c] = W2[c0 + c]; }
  float p[4] = {};
#pragma unroll
  for (int r = 0; r < 4; ++r)
#pragma unroll
    for (int c = 0; c < 8; ++c) {
      float v = acc[r][c] + b1v[c];
      v = v > 0.0f ? v : 0.01f * v;
      p[r] += v * w2v[c];
    }
#pragma unroll
  for (int o = 8; o > 0; o >>= 1)
#pragma unroll
    for (int r = 0; r < 4; ++r)
      p[r] += __shfl_xor(p[r], o, 16);
  if (tx == 0) {
    int node = node_base + row0 + ty * 4;
#pragma unroll
    for (int r = 0; r < 4; ++r)
      unsafeAtomicAdd(&z[node + r], p[r]);
  }
}

__global__ void k_mask_init(int* __restrict__ mask) {
  int n = blockIdx.x * 256 + threadIdx.x;
  if (n < NN) mask[n] = -1;
}

__global__ void k_score_init(const float* __restrict__ dinv, const float* __restrict__ z,
                             const float* __restrict__ b2, float* __restrict__ score) {
  int n = blockIdx.x * 256 + threadIdx.x;
  if (n < NN) score[n] = b2[0] + dinv[n] * dinv[n] * z[n];
}

__global__ void k_score_edges(const int* __restrict__ ei, const float* __restrict__ w,
                              const float* __restrict__ dinv, const float* __restrict__ z,
                              float* __restrict__ score) {
  int e = blockIdx.x * 256 + threadIdx.x;
  if (e < NE) {
    int r = ei[e], c = ei[NE + e];
    unsafeAtomicAdd(&score[c], w[e] * dinv[r] * dinv[c] * z[r]);
  }
}

__device__ void bitonic(unsigned long long* keys, int n, int t, int nt) {
  for (int k = 2; k <= n; k <<= 1)
    for (int jj = k >> 1; jj > 0; jj >>= 1) {
      __syncthreads();
      for (int i = t; i < n; i += nt) {
        int ixj = i ^ jj;
        if (ixj > i) {
          unsigned long long a = keys[i], c = keys[ixj];
          bool up = ((i & k) == 0);
          if ((a > c) == up) { keys[i] = c; keys[ixj] = a; }
        }
      }
    }
  __syncthreads();
}

// One block per graph: sentence top-3 (of 64) + other top-480 (of 960),
// lax.top_k order: value desc, index asc. Emits perm/score_perm/batch_out/
// sentence outputs and scatters mask.
__global__ __launch_bounds__(256) void k_topk(const float* __restrict__ score,
                                              int* __restrict__ mask,
                                              float* __restrict__ out) {
  __shared__ unsigned long long keys[1024];
  int b = blockIdx.x, t = threadIdx.x;
  int base = b << 10;
  if (t < 64) {
    float v = score[base + t];
    keys[t] = ((unsigned long long)(~monof(v)) << 32) | (unsigned)t;
    out[O6 + b * 64 + t] = v;            // sentence_scores
    out[O7 + b * 64 + t] = (float)b;     // sentence_batch
  }
  __syncthreads();
  bitonic(keys, 64, t, 256);
  if (t < 3) {
    int idx = (int)(keys[t] & 0xFFFFFFFFull);
    int node = base + idx;
    int pos = b * 3 + t;
    mask[node] = pos;
    out[O4 + pos] = (float)node;
    out[O5 + pos] = score[node];
    out[O3 + pos] = (float)b;
  }
  __syncthreads();
  for (int i = t; i < 1024; i += 256) {
    if (i < 960) {
      float v = score[base + 64 + i];
      keys[i] = ((unsigned long long)(~monof(v)) << 32) | (unsigned)i;
    } else {
      keys[i] = 0xFFFFFFFFFFFFFFFFull;   // pad sorts last
    }
  }
  __syncthreads();
  bitonic(keys, 1024, t, 256);
  for (int r = t; r < 480; r += 256) {
    int idx = (int)(keys[r] & 0xFFFFFFFFull);
    int node = base + 64 + idx;
    int pos = 192 + b * 480 + r;
    mask[node] = pos;
    out[O4 + pos] = (float)node;
    out[O5 + pos] = score[node];
    out[O3 + pos] = (float)b;
  }
}

__global__ void k_edges(const int* __restrict__ ei, const float* __restrict__ w,
                        const int* __restrict__ mask, float* __restrict__ out) {
  int e = blockIdx.x * 256 + threadIdx.x;
  if (e >= NE) return;
  int nr = mask[ei[e]];
  int nc = mask[ei[NE + e]];
  bool keep = (nr >= 0) && (nc >= 0);
  out[O1 + e]      = keep ? (float)nr : -1.0f;
  out[O1 + NE + e] = keep ? (float)nc : -1.0f;
  out[O2 + e]      = keep ? w[e] : 0.0f;
  out[O8 + e]      = keep ? 1.0f : 0.0f;
}

__global__ void k_xout(const float* __restrict__ x, const float* __restrict__ permF,
                       const float* __restrict__ scoreP, float* __restrict__ out) {
  int i = blockIdx.x;                 // 30912 rows
  int node = (int)permF[i];
  float s = scoreP[i];
  const float4* xr = (const float4*)&x[node * 256];
  float4* o = (float4*)&out[i * 256];
  float4 v = xr[threadIdx.x];
  o[threadIdx.x] = make_float4(v.x * s, v.y * s, v.z * s, v.w * s);
}

extern "C" void kernel_launch(void* const* d_in, const int* in_sizes, int n_in,
                              void* d_out, int out_size, void* d_ws, size_t ws_size,
                              hipStream_t stream) {
  (void)in_sizes; (void)n_in; (void)out_size; (void)d_ws; (void)ws_size;
  const float* x  = (const float*)d_in[0];
  const int*   ei = (const int*)d_in[1];
  const float* w  = (const float*)d_in[2];
  const float* W1 = (const float*)d_in[4];
  const float* b1 = (const float*)d_in[5];
  const float* W2 = (const float*)d_in[6];
  const float* b2 = (const float*)d_in[7];
  float* out   = (float*)d_out;
  float* ybuf  = out;                 // scratch, dies before outputs
  float* deg   = out + DEG_OFF;       // becomes dinv in-place
  float* z     = out + Z_OFF;
  float* score = out + SCORE_OFF;
  int*   mask  = (int*)d_out;         // [0,65536) ints, after ybuf dies

  k_init<<<256, 256, 0, stream>>>(deg, z);
  k_deg<<<2048, 256, 0, stream>>>(ei, w, deg);
  k_dinv<<<256, 256, 0, stream>>>(deg);
  for (int ch = 0; ch < 2; ++ch) {
    k_aggx<<<512, 256, 65536, stream>>>(x, ei, w, deg, ybuf, ch * 32, 32);
    k_gemm<<<2048, 256, 0, stream>>>(ybuf, W1, b1, W2, z, ch * 32768);
  }
  k_mask_init<<<256, 256, 0, stream>>>(mask);
  k_score_init<<<256, 256, 0, stream>>>(deg, z, b2, score);
  k_score_edges<<<2048, 256, 0, stream>>>(ei, w, deg, z, score);
  k_topk<<<64, 256, 0, stream>>>(score, mask, out);
  k_edges<<<2048, 256, 0, stream>>>(ei, w, mask, out);
  k_xout<<<30912, 64, 0, stream>>>(x, out + O4, out + O5, out);
}

// Round 2
// 993.164 us; speedup vs baseline: 1.0090x; 1.0090x over previous
//
#include <hip/hip_runtime.h>

// Problem constants
#define NN   65536      // N nodes
#define NE   524288     // E edges
#define EPG  8192       // edges per graph

// Output float offsets in d_out (total 10111552 floats)
#define O1 7913472      // ei_new (2*E)
#define O2 8962048      // ea_new (E)
#define O3 9486336      // batch_out (30912)
#define O4 9517248      // perm (30912)
#define O5 9548160      // score_perm (30912)
#define O6 9579072      // sentence_scores (4096)
#define O7 9583168      // sentence_batch (4096)
#define O8 9587264      // keep (E)

// Scratch placement (float offsets), lifetime-verified:
//  ybuf   [0, 8388608)        dies after last k_gemm
//  packed [8388608, 8912896)  dies after k_score_edges (k_edges overwrites O1 span)
//  coef   [8912896, 9437184)  dies after k_score_edges (k_edges overwrites O2 span)
//  deg    [9437184, 9502720)  dies after k_score_edges (k_topk writes O3 span)
//  z      [9502720, 9568256)  dies after k_score_edges
//  score  [65536, 131072)     written after ybuf dies; dies after k_topk (k_xout last)
//  mask   ints [0, 65536)     written after ybuf dies; read k_edges; k_xout overwrites last
#define PACK_OFF 8388608
#define COEF_OFF 8912896
#define DEG_OFF  9437184
#define Z_OFF    9502720
#define SCORE_OFF 65536

__device__ __forceinline__ unsigned monof(float f) {
  unsigned u = __float_as_uint(f);
  return (u & 0x80000000u) ? ~u : (u | 0x80000000u);  // ascending monotone map
}

__global__ void k_init(float* __restrict__ deg, float* __restrict__ z) {
  int n = blockIdx.x * 256 + threadIdx.x;
  if (n < NN) { deg[n] = 1.0f; z[n] = 0.0f; }
}

__global__ void k_deg(const int* __restrict__ ei, const float* __restrict__ w,
                      float* __restrict__ deg) {
  int e = blockIdx.x * 256 + threadIdx.x;
  if (e < NE) unsafeAtomicAdd(&deg[ei[NE + e]], w[e]);
}

__global__ void k_dinv(float* __restrict__ deg) {
  int n = blockIdx.x * 256 + threadIdx.x;
  if (n < NN) { float d = deg[n]; deg[n] = d > 0.0f ? 1.0f / sqrtf(d) : 0.0f; }
}

// packed[e] = (global_row << 16) | local_col ; coef[e] = w[e]*dinv[row]
__global__ void k_pack(const int* __restrict__ ei, const float* __restrict__ w,
                       const float* __restrict__ dinv,
                       unsigned* __restrict__ packed, float* __restrict__ coef) {
  int e = blockIdx.x * 256 + threadIdx.x;
  if (e < NE) {
    int r = ei[e];
    packed[e] = ((unsigned)r << 16) | (unsigned)(ei[NE + e] & 1023);
    coef[e] = w[e] * dinv[r];
  }
}

// Aggregate x over normalized adjacency into ybuf (chunk of 32 graphs).
// One block = (graph g, 8-column chunk cc). acc[1024][8] = 32 KB -> 4 blocks/CU.
// 8-lane groups own one edge; 8 edges per group in flight (branchless).
__global__ __launch_bounds__(256, 4) void k_aggx(const float* __restrict__ x,
    const unsigned* __restrict__ packed, const float* __restrict__ coef,
    const float* __restrict__ dinv, float* __restrict__ ybuf, int gbase) {
  __shared__ float acc[1024 * 8];  // 32 KB
  int bid = blockIdx.x;
  int g  = bid & 31;               // graph g on XCD g%8 -> 4 graphs (4MB x) per XCD L2
  int cc = bid >> 5;               // 32 chunks of 8 columns
  int gg = gbase + g;
  int c0 = cc * 8;
  int t = threadIdx.x;
  int nbase = gg << 10;
  // self-loop init: acc[n][j] = dinv[node]*x[node][c0+j]
  for (int s = 0; s < 32; ++s) {
    int i = t + s * 256;
    int n = i >> 3, jj = i & 7;
    acc[i] = dinv[nbase + n] * x[(nbase + n) * 256 + c0 + jj];
  }
  __syncthreads();
  int j = t & 7, slot = t >> 3;             // 32 groups of 8 lanes
  int ebase = gg * EPG + slot * 256;        // contiguous 256 edges per group
  for (int it = 0; it < 32; ++it) {
    int base = ebase + it * 8;
    unsigned pk[8]; float cf[8], xv[8];
#pragma unroll
    for (int u = 0; u < 8; ++u) pk[u] = packed[base + u];
#pragma unroll
    for (int u = 0; u < 8; ++u) cf[u] = coef[base + u];
#pragma unroll
    for (int u = 0; u < 8; ++u) xv[u] = x[(pk[u] >> 16) * 256 + c0 + j];
#pragma unroll
    for (int u = 0; u < 8; ++u)
      atomicAdd(&acc[(pk[u] & 1023) * 8 + j], cf[u] * xv[u]);
  }
  __syncthreads();
  for (int s = 0; s < 32; ++s) {
    int i = t + s * 256;
    int n = i >> 3;
    ybuf[((g << 10) + n) * 256 + c0 + (i & 7)] = dinv[nbase + n] * acc[i];
  }
}

// fp32 GEMM y(32768x256) @ W1(256x512), fused +b1 -> LeakyReLU -> dot W2 -> atomic z
// BM=64, BN=128, BK=32, 256 threads, acc 4x8 per thread.
__global__ __launch_bounds__(256) void k_gemm(const float* __restrict__ ybuf,
    const float* __restrict__ W1, const float* __restrict__ b1,
    const float* __restrict__ W2, float* __restrict__ z, int node_base) {
  __shared__ float As[32][68];    // [k][row], padded
  __shared__ float Bs[32][132];   // [k][col], padded
  int bx = blockIdx.x & 3;        // 4 col-blocks of 128
  int by = blockIdx.x >> 2;       // 512 row-blocks of 64
  int t = threadIdx.x;
  int tx = t & 15, ty = t >> 4;
  int row0 = by * 64;
  float acc[4][8] = {};
  for (int kt = 0; kt < 256; kt += 32) {
    __syncthreads();
#pragma unroll
    for (int s = 0; s < 8; ++s) {         // A: 64x32
      int i = t + s * 256;
      As[i & 31][i >> 5] = ybuf[(row0 + (i >> 5)) * 256 + kt + (i & 31)];
    }
#pragma unroll
    for (int s = 0; s < 16; ++s) {        // B: 32x128
      int i = t + s * 256;
      Bs[i >> 7][i & 127] = W1[(kt + (i >> 7)) * 512 + bx * 128 + (i & 127)];
    }
    __syncthreads();
#pragma unroll
    for (int kk = 0; kk < 32; ++kk) {
      float4 a4  = *(const float4*)&As[kk][ty * 4];
      float4 b4a = *(const float4*)&Bs[kk][tx * 4];        // stride-4: 2-way, free
      float4 b4b = *(const float4*)&Bs[kk][tx * 4 + 64];
      float a[4]  = {a4.x, a4.y, a4.z, a4.w};
      float bb[8] = {b4a.x, b4a.y, b4a.z, b4a.w, b4b.x, b4b.y, b4b.z, b4b.w};
#pragma unroll
      for (int r = 0; r < 4; ++r)
#pragma unroll
        for (int c = 0; c < 8; ++c)
          acc[r][c] += a[r] * bb[c];
    }
  }
  // epilogue: +b1, LeakyReLU, dot W2, reduce over tx, atomic into z
  int ca = bx * 128 + tx * 4, cb = ca + 64;
  float b1v[8], w2v[8];
#pragma unroll
  for (int c = 0; c < 8; ++c) {
    int col = (c < 4) ? ca + c : cb + (c - 4);
    b1v[c] = b1[col]; w2v[c] = W2[col];
  }
  float p[4] = {};
#pragma unroll
  for (int r = 0; r < 4; ++r)
#pragma unroll
    for (int c = 0; c < 8; ++c) {
      float v = acc[r][c] + b1v[c];
      v = v > 0.0f ? v : 0.01f * v;
      p[r] += v * w2v[c];
    }
#pragma unroll
  for (int o = 8; o > 0; o >>= 1)
#pragma unroll
    for (int r = 0; r < 4; ++r)
      p[r] += __shfl_xor(p[r], o, 16);
  if (tx == 0) {
    int node = node_base + row0 + ty * 4;
#pragma unroll
    for (int r = 0; r < 4; ++r)
      unsafeAtomicAdd(&z[node + r], p[r]);
  }
}

__global__ void k_mask_init(int* __restrict__ mask) {
  int n = blockIdx.x * 256 + threadIdx.x;
  if (n < NN) mask[n] = -1;
}

__global__ void k_score_init(const float* __restrict__ dinv, const float* __restrict__ z,
                             const float* __restrict__ b2, float* __restrict__ score) {
  int n = blockIdx.x * 256 + threadIdx.x;
  if (n < NN) score[n] = b2[0] + dinv[n] * dinv[n] * z[n];
}

__global__ void k_score_edges(const unsigned* __restrict__ packed,
                              const float* __restrict__ coef,
                              const float* __restrict__ dinv, const float* __restrict__ z,
                              float* __restrict__ score) {
  int e = blockIdx.x * 256 + threadIdx.x;
  if (e < NE) {
    unsigned pk = packed[e];
    int r = pk >> 16;
    int c = ((e >> 13) << 10) | (pk & 1023);
    unsafeAtomicAdd(&score[c], coef[e] * dinv[c] * z[r]);
  }
}

__device__ void bitonic(unsigned long long* keys, int n, int t, int nt) {
  for (int k = 2; k <= n; k <<= 1)
    for (int jj = k >> 1; jj > 0; jj >>= 1) {
      __syncthreads();
      for (int i = t; i < n; i += nt) {
        int ixj = i ^ jj;
        if (ixj > i) {
          unsigned long long a = keys[i], c = keys[ixj];
          bool up = ((i & k) == 0);
          if ((a > c) == up) { keys[i] = c; keys[ixj] = a; }
        }
      }
    }
  __syncthreads();
}

// One block per graph: sentence top-3 (of 64) + other top-480 (of 960),
// lax.top_k order: value desc, index asc.
__global__ __launch_bounds__(256) void k_topk(const float* __restrict__ score,
                                              int* __restrict__ mask,
                                              float* __restrict__ out) {
  __shared__ unsigned long long keys[1024];
  int b = blockIdx.x, t = threadIdx.x;
  int base = b << 10;
  if (t < 64) {
    float v = score[base + t];
    keys[t] = ((unsigned long long)(~monof(v)) << 32) | (unsigned)t;
    out[O6 + b * 64 + t] = v;            // sentence_scores
    out[O7 + b * 64 + t] = (float)b;     // sentence_batch
  }
  __syncthreads();
  bitonic(keys, 64, t, 256);
  if (t < 3) {
    int idx = (int)(keys[t] & 0xFFFFFFFFull);
    int node = base + idx;
    int pos = b * 3 + t;
    mask[node] = pos;
    out[O4 + pos] = (float)node;
    out[O5 + pos] = score[node];
    out[O3 + pos] = (float)b;
  }
  __syncthreads();
  for (int i = t; i < 1024; i += 256) {
    if (i < 960) {
      float v = score[base + 64 + i];
      keys[i] = ((unsigned long long)(~monof(v)) << 32) | (unsigned)i;
    } else {
      keys[i] = 0xFFFFFFFFFFFFFFFFull;   // pad sorts last
    }
  }
  __syncthreads();
  bitonic(keys, 1024, t, 256);
  for (int r = t; r < 480; r += 256) {
    int idx = (int)(keys[r] & 0xFFFFFFFFull);
    int node = base + 64 + idx;
    int pos = 192 + b * 480 + r;
    mask[node] = pos;
    out[O4 + pos] = (float)node;
    out[O5 + pos] = score[node];
    out[O3 + pos] = (float)b;
  }
}

__global__ void k_edges(const int* __restrict__ ei, const float* __restrict__ w,
                        const int* __restrict__ mask, float* __restrict__ out) {
  int e = blockIdx.x * 256 + threadIdx.x;
  if (e >= NE) return;
  int nr = mask[ei[e]];
  int nc = mask[ei[NE + e]];
  bool keep = (nr >= 0) && (nc >= 0);
  out[O1 + e]      = keep ? (float)nr : -1.0f;
  out[O1 + NE + e] = keep ? (float)nc : -1.0f;
  out[O2 + e]      = keep ? w[e] : 0.0f;
  out[O8 + e]      = keep ? 1.0f : 0.0f;
}

__global__ void k_xout(const float* __restrict__ x, const float* __restrict__ permF,
                       const float* __restrict__ scoreP, float* __restrict__ out) {
  int i = blockIdx.x;                 // 30912 rows
  int node = (int)permF[i];
  float s = scoreP[i];
  const float4* xr = (const float4*)&x[node * 256];
  float4* o = (float4*)&out[i * 256];
  float4 v = xr[threadIdx.x];
  o[threadIdx.x] = make_float4(v.x * s, v.y * s, v.z * s, v.w * s);
}

extern "C" void kernel_launch(void* const* d_in, const int* in_sizes, int n_in,
                              void* d_out, int out_size, void* d_ws, size_t ws_size,
                              hipStream_t stream) {
  (void)in_sizes; (void)n_in; (void)out_size; (void)d_ws; (void)ws_size;
  const float* x  = (const float*)d_in[0];
  const int*   ei = (const int*)d_in[1];
  const float* w  = (const float*)d_in[2];
  const float* W1 = (const float*)d_in[4];
  const float* b1 = (const float*)d_in[5];
  const float* W2 = (const float*)d_in[6];
  const float* b2 = (const float*)d_in[7];
  float* out    = (float*)d_out;
  float* ybuf   = out;
  unsigned* packed = (unsigned*)(out + PACK_OFF);
  float* coef   = out + COEF_OFF;
  float* deg    = out + DEG_OFF;      // becomes dinv in-place
  float* z      = out + Z_OFF;
  float* score  = out + SCORE_OFF;
  int*   mask   = (int*)d_out;        // ints [0,65536), after ybuf dies

  k_init<<<256, 256, 0, stream>>>(deg, z);
  k_deg<<<2048, 256, 0, stream>>>(ei, w, deg);
  k_dinv<<<256, 256, 0, stream>>>(deg);
  k_pack<<<2048, 256, 0, stream>>>(ei, w, deg, packed, coef);
  for (int ch = 0; ch < 2; ++ch) {
    k_aggx<<<1024, 256, 0, stream>>>(x, packed, coef, deg, ybuf, ch * 32);
    k_gemm<<<2048, 256, 0, stream>>>(ybuf, W1, b1, W2, z, ch * 32768);
  }
  k_mask_init<<<256, 256, 0, stream>>>(mask);
  k_score_init<<<256, 256, 0, stream>>>(deg, z, b2, score);
  k_score_edges<<<2048, 256, 0, stream>>>(packed, coef, deg, z, score);
  k_topk<<<64, 256, 0, stream>>>(score, mask, out);
  k_edges<<<2048, 256, 0, stream>>>(ei, w, mask, out);
  k_xout<<<30912, 64, 0, stream>>>(x, out + O4, out + O5, out);
}